// Round 8
// baseline (118.298 us; speedup 1.0000x reference)
//
#include <hip/hip_runtime.h>
#include <stdint.h>

typedef _Float16 half_t;
typedef __attribute__((ext_vector_type(8))) _Float16 f16x8;
typedef __attribute__((ext_vector_type(4))) _Float16 f16x4;
typedef __attribute__((ext_vector_type(2))) __fp16 fp16x2;
typedef __attribute__((ext_vector_type(4))) float f32x4;

#define DEVI __device__ __forceinline__

static constexpr int Bn = 4, Cc = 256, Nn = 4096, PD = 32;
static constexpr float L2E = 1.44269504089f;

// persistent f16 intermediates (module-scope device memory; fully rewritten every call)
__device__ half_t g_Q[(size_t)Bn * Nn * PD];   // [b][n][d]
__device__ half_t g_K[(size_t)Bn * Nn * PD];   // [b][n][d]  (= k^T)
__device__ half_t g_V[(size_t)Bn * Cc * Nn];   // [b][e][n]

DEVI f16x8 cvt8(float4 a, float4 b) {
    f16x8 r;
    r[0] = (_Float16)a.x; r[1] = (_Float16)a.y; r[2] = (_Float16)a.z; r[3] = (_Float16)a.w;
    r[4] = (_Float16)b.x; r[5] = (_Float16)b.y; r[6] = (_Float16)b.z; r[7] = (_Float16)b.w;
    return r;
}

// async global->LDS, 16B per lane; LDS dest is wave-uniform base + lane*16
DEVI void gll16(const void* g, void* l) {
    auto gp = (const __attribute__((address_space(1))) uint32_t*)(uintptr_t)g;
    auto lp = (__attribute__((address_space(3))) uint32_t*)(uintptr_t)l;
    __builtin_amdgcn_global_load_lds(gp, lp, 16, 0, 0);
}

// ---------------- projection: Q,K,V = W @ x (+bias), f16 outputs ----------------
__global__ __launch_bounds__(256, 1) void proj_kernel(
    const float* __restrict__ x,
    const float* __restrict__ Wq, const float* __restrict__ bq,
    const float* __restrict__ Wk, const float* __restrict__ bk,
    const float* __restrict__ Wv, const float* __restrict__ bv)
{
    __shared__ __align__(16) half_t xt[64 * 40];   // [n][c] tile, pad 32->40

    const int b    = blockIdx.x >> 6;
    const int n0   = (blockIdx.x & 63) * 64;
    const int t    = threadIdx.x;
    const int w    = t >> 6;
    const int lane = t & 63;
    const int l15  = lane & 15, g = lane >> 4;

    f32x4 qk_acc[4] = {};
    f32x4 v_acc[4][4] = {};

    const float* wrow_qk = (w < 2) ? (Wq + (size_t)(16 * w + l15) * Cc)
                                   : (Wk + (size_t)(16 * (w - 2) + l15) * Cc);

    for (int cs = 0; cs < 8; ++cs) {
        const int c0 = cs * 32;
        {
            const int nl = t & 63;
            const int cg = t >> 6;
            const float* xp = x + ((size_t)(b * Cc + c0 + cg * 8)) * Nn + n0 + nl;
            float f[8];
#pragma unroll
            for (int q = 0; q < 8; ++q) f[q] = xp[(size_t)q * Nn];
            f16x4 h0, h1;
#pragma unroll
            for (int q = 0; q < 4; ++q) { h0[q] = (_Float16)f[q]; h1[q] = (_Float16)f[q + 4]; }
            *(f16x4*)&xt[nl * 40 + cg * 8]     = h0;
            *(f16x4*)&xt[nl * 40 + cg * 8 + 4] = h1;
        }
        __syncthreads();

        f16x8 xf[4];
#pragma unroll
        for (int nf = 0; nf < 4; ++nf)
            xf[nf] = *(const f16x8*)&xt[(nf * 16 + l15) * 40 + g * 8];

        {
            const float* wp = wrow_qk + c0 + g * 8;
            const f16x8 af = cvt8(*(const float4*)wp, *(const float4*)(wp + 4));
#pragma unroll
            for (int nt = 0; nt < 4; ++nt)
                qk_acc[nt] = __builtin_amdgcn_mfma_f32_16x16x32_f16(af, xf[nt], qk_acc[nt], 0, 0, 0);
        }
#pragma unroll
        for (int et = 0; et < 4; ++et) {
            const int e = (w * 4 + et) * 16 + l15;
            const float* wp = Wv + (size_t)e * Cc + c0 + g * 8;
            const f16x8 wf = cvt8(*(const float4*)wp, *(const float4*)(wp + 4));
#pragma unroll
            for (int nf = 0; nf < 4; ++nf)
                v_acc[et][nf] = __builtin_amdgcn_mfma_f32_16x16x32_f16(xf[nf], wf, v_acc[et][nf], 0, 0, 0);
        }
        __syncthreads();
    }

    {
        const float* bias = (w < 2) ? bq : bk;
        const int dbase = 16 * (w & 1) + 4 * g;
        float bb[4];
#pragma unroll
        for (int r = 0; r < 4; ++r) bb[r] = bias[dbase + r];
        half_t* dst = (w < 2) ? g_Q : g_K;
#pragma unroll
        for (int nt = 0; nt < 4; ++nt) {
            const int n = n0 + nt * 16 + l15;
            f16x4 h;
#pragma unroll
            for (int r = 0; r < 4; ++r) h[r] = (_Float16)(qk_acc[nt][r] + bb[r]);
            *(f16x4*)&dst[((size_t)b * Nn + n) * PD + dbase] = h;
        }
    }
#pragma unroll
    for (int et = 0; et < 4; ++et) {
        const int e = (w * 4 + et) * 16 + l15;
        const float bve = bv[e];
#pragma unroll
        for (int nf = 0; nf < 4; ++nf) {
            const int n = n0 + nf * 16 + 4 * g;
            f16x4 h;
#pragma unroll
            for (int r = 0; r < 4; ++r) h[r] = (_Float16)(v_acc[et][nf][r] + bve);
            *(f16x4*)&g_V[((size_t)b * Cc + e) * Nn + n] = h;
        }
    }
}

// ---------------- fused flash attention + residual (v7: 4 blocks/CU) -------------
// Block = 32m x 128e, 4 waves (mh: 16m, kk: 32n-half).  Grid 1024 = 4b x 2eh x
// 128mt -> 4 blocks/CU, 16 waves/CU (4/SIMD) for stall hiding.  R_QK = 2
// (unchanged).  Wave-local softmax (independent run_m/run_l per kk; exact
// exp2-merge in epilogue).  V tile [128e][64n] staged via global_load_lds with
// pre-swizzled source; counted vmcnt(2) + raw barrier per iter.
__global__ __launch_bounds__(256, 4) void attn_kernel(
    const float* __restrict__ x, const float* __restrict__ gamma_p, float* __restrict__ out)
{
    __shared__ __align__(16) half_t V_lds[2][128 * 64];   // linear [e][n], 32KB
    __shared__ __align__(16) half_t P_lds[4][16 * 40];    // per-wave [m][n], padded
    __shared__ float mx[2][2][16];                        // [kk][mh][m-local] run_m
    __shared__ float lx[2][2][16];                        // [kk][mh][m-local] run_l

    const int blk = blockIdx.x;
    const int grp = blk & 7;                // (b, eh): one per XCD (round-robin)
    const int mt  = blk >> 3;               // [0,128)
    const int b   = grp >> 1;
    const int eh  = grp & 1;
    const int e0  = eh * 128;

    const int t    = threadIdx.x;
    const int w    = t >> 6;
    const int lane = t & 63;
    const int l15  = lane & 15, g = lane >> 4;
    const int mh   = w >> 1, kk = w & 1;
    const int mrow0 = mt * 32 + mh * 16;

    const half_t* Kb  = g_K + (size_t)b * Nn * PD;
    const half_t* Vbg = g_V + (size_t)b * Cc * Nn;

    const f16x8 qf = *(const f16x8*)&g_Q[((size_t)b * Nn + mrow0 + l15) * PD + g * 8];

    // V gll: lane covers (row = lane>>3, chunk lane&7); source col pre-swizzled
    const int vrow = lane >> 3;
    const int vcol = (((lane & 7) ^ vrow) * 8);
    const half_t* vptr[4];
#pragma unroll
    for (int ch = 0; ch < 4; ++ch)
        vptr[ch] = Vbg + (size_t)(e0 + w * 32 + ch * 8 + vrow) * Nn + vcol;

    f32x4 acc[8] = {};                       // [et]; rows m=4g+r, col e=et*16+l15
    float run_m = -1e30f, run_l = 0.f;

    const int xorv = (kk * 32 + 8 * g) ^ ((l15 & 7) * 8);
    const f32x4 zero = {0.f, 0.f, 0.f, 0.f};

    f32x4 s[2];                              // scores of CURRENT tile (pipelined)
    f16x8 kq[2];                             // K frags for NEXT tile's QK

    // ---- prologue: QK(0); gll V(0); K(1) prefetch ----
    {
        const half_t* kp0 = Kb + (size_t)(kk * 32 + l15) * PD + g * 8;
        f16x8 k0a = *(const f16x8*)kp0;
        f16x8 k0b = *(const f16x8*)(kp0 + 16 * PD);
        s[0] = __builtin_amdgcn_mfma_f32_16x16x32_f16(k0a, qf, zero, 0, 0, 0);
        s[1] = __builtin_amdgcn_mfma_f32_16x16x32_f16(k0b, qf, zero, 0, 0, 0);
    }
#pragma unroll
    for (int ch = 0; ch < 4; ++ch)
        gll16(vptr[ch], &V_lds[0][(w * 32 + ch * 8) * 64]);
    const half_t* kp = Kb + (size_t)(64 + kk * 32 + l15) * PD + g * 8;
    kq[0] = *(const f16x8*)kp;
    kq[1] = *(const f16x8*)(kp + 16 * PD);

    constexpr int NT = Nn / 64;
    for (int i = 0; i < NT; ++i) {
        const int buf = i & 1;
        const bool more = (i + 1 < NT);

        // counted drain: own gll(tile i) done; K prefetch stays in flight.
        asm volatile("s_waitcnt vmcnt(2)" ::: "memory");
        __builtin_amdgcn_s_barrier();
        __builtin_amdgcn_sched_barrier(0);

        // ---- softmax on pre-computed s (wave-local, 16 m-rows = l15) ----
        float tm;
        {
            float a0 = fmaxf(s[0][0], s[0][1]), a1 = fmaxf(s[0][2], s[0][3]);
            float a2 = fmaxf(s[1][0], s[1][1]), a3 = fmaxf(s[1][2], s[1][3]);
            tm = fmaxf(fmaxf(a0, a1), fmaxf(a2, a3));
            tm = fmaxf(tm, __shfl_xor(tm, 16));
            tm = fmaxf(tm, __shfl_xor(tm, 32));
        }
        float alpha = 1.f;
        if (__any(tm > run_m + 8.f)) {
            const float nm = fmaxf(run_m, tm);
            alpha = __builtin_amdgcn_exp2f((run_m - nm) * L2E);
            run_m = nm;
            float a4[4];
#pragma unroll
            for (int r = 0; r < 4; ++r) a4[r] = __shfl(alpha, 4 * g + r);
#pragma unroll
            for (int et = 0; et < 8; ++et)
#pragma unroll
                for (int r = 0; r < 4; ++r) acc[et][r] *= a4[r];
        }

        {
            const float nms = run_m * L2E;
            float rs = 0.f;
#pragma unroll
            for (int tt = 0; tt < 2; ++tt) {
                float p0 = __builtin_amdgcn_exp2f(s[tt][0] * L2E - nms);
                float p1 = __builtin_amdgcn_exp2f(s[tt][1] * L2E - nms);
                float p2 = __builtin_amdgcn_exp2f(s[tt][2] * L2E - nms);
                float p3 = __builtin_amdgcn_exp2f(s[tt][3] * L2E - nms);
                rs += (p0 + p1) + (p2 + p3);
                const fp16x2 ha = __builtin_amdgcn_cvt_pkrtz(p0, p1);
                const fp16x2 hb = __builtin_amdgcn_cvt_pkrtz(p2, p3);
                f16x4 h;
                h[0] = (_Float16)ha[0]; h[1] = (_Float16)ha[1];
                h[2] = (_Float16)hb[0]; h[3] = (_Float16)hb[1];
                *(f16x4*)&P_lds[w][l15 * 40 + tt * 16 + 4 * g] = h;
            }
            rs += __shfl_xor(rs, 16);
            rs += __shfl_xor(rs, 32);
            run_l = run_l * alpha + rs;
        }

        const f16x8 pf = *(const f16x8*)&P_lds[w][l15 * 40 + g * 8];

        // issue gll for tile i+1 into the other buffer
        if (more) {
#pragma unroll
            for (int ch = 0; ch < 4; ++ch) {
                vptr[ch] += 64;
                gll16(vptr[ch], &V_lds[buf ^ 1][(w * 32 + ch * 8) * 64]);
            }
        }

        // ---- PV over wave's 32n half ----
        __builtin_amdgcn_s_setprio(1);
#pragma unroll
        for (int et = 0; et < 8; ++et) {
            const int el = et * 16 + l15;
            const f16x8 vf = *(const f16x8*)&V_lds[buf][el * 64 + xorv];
            acc[et] = __builtin_amdgcn_mfma_f32_16x16x32_f16(pf, vf, acc[et], 0, 0, 0);
        }
        __builtin_amdgcn_s_setprio(0);

        // ---- QK for tile i+1 ----
        if (more) {
            s[0] = __builtin_amdgcn_mfma_f32_16x16x32_f16(kq[0], qf, zero, 0, 0, 0);
            s[1] = __builtin_amdgcn_mfma_f32_16x16x32_f16(kq[1], qf, zero, 0, 0, 0);
            if (i + 2 < NT) {
                kp += 64 * PD;
                kq[0] = *(const f16x8*)kp;
                kq[1] = *(const f16x8*)(kp + 16 * PD);
            }
        }
    }

    // ---- epilogue: publish (m,l), merge kk-pair with exact m-correction ----
    if (lane < 16) {
        mx[kk][mh][lane] = run_m;
        lx[kk][mh][lane] = run_l;
    }
    __syncthreads();

    float sscl[4], linv[4];
    {
        const float mo = mx[kk ^ 1][mh][l15];
        const float lo = lx[kk ^ 1][mh][l15];
        const float M  = fmaxf(run_m, mo);
        const float ss = __builtin_amdgcn_exp2f((run_m - M) * L2E);
        const float so = __builtin_amdgcn_exp2f((mo - M) * L2E);
        const float inv = 1.0f / (run_l * ss + lo * so);
#pragma unroll
        for (int r = 0; r < 4; ++r) {
            sscl[r] = __shfl(ss, 4 * g + r);
            linv[r] = __shfl(inv, 4 * g + r);
        }
    }

    const float gm = gamma_p[0];
    float* mrg = (float*)&V_lds[0][0];            // 2mh x 128e x 20 floats = 20.5KB
    __syncthreads();                              // all V reads done before overwrite
    if (kk == 1) {
#pragma unroll
        for (int et = 0; et < 8; ++et) {
            const int el = et * 16 + l15;
            f32x4 v;
#pragma unroll
            for (int r = 0; r < 4; ++r) v[r] = acc[et][r] * sscl[r];
            *(f32x4*)&mrg[(size_t)(mh * 128 + el) * 20 + 4 * g] = v;
        }
    }
    __syncthreads();
    if (kk == 0) {
#pragma unroll
        for (int et = 0; et < 8; ++et) {
            const int el = et * 16 + l15;
            const int e  = e0 + el;
            const f32x4 part = *(const f32x4*)&mrg[(size_t)(mh * 128 + el) * 20 + 4 * g];
            const size_t idx = ((size_t)b * Cc + e) * Nn + (mrow0 + 4 * g);
            const float4 xin = *(const float4*)&x[idx];
            float4 o;
            o.x = gm * (acc[et][0] * sscl[0] + part[0]) * linv[0] + xin.x;
            o.y = gm * (acc[et][1] * sscl[1] + part[1]) * linv[1] + xin.y;
            o.z = gm * (acc[et][2] * sscl[2] + part[2]) * linv[2] + xin.z;
            o.w = gm * (acc[et][3] * sscl[3] + part[3]) * linv[3] + xin.w;
            *(float4*)&out[idx] = o;
        }
    }
}

extern "C" void kernel_launch(void* const* d_in, const int* in_sizes, int n_in,
                              void* d_out, int out_size, void* d_ws, size_t ws_size,
                              hipStream_t stream) {
    (void)in_sizes; (void)n_in; (void)out_size; (void)d_ws; (void)ws_size;
    const float* x  = (const float*)d_in[0];
    const float* Wq = (const float*)d_in[1];
    const float* bq = (const float*)d_in[2];
    const float* Wk = (const float*)d_in[3];
    const float* bk = (const float*)d_in[4];
    const float* Wv = (const float*)d_in[5];
    const float* bv = (const float*)d_in[6];
    const float* gm = (const float*)d_in[7];
    float* out = (float*)d_out;

    proj_kernel<<<256, 256, 0, stream>>>(x, Wq, bq, Wk, bk, Wv, bv);
    attn_kernel<<<1024, 256, 0, stream>>>(x, gm, out);
}

// Round 11
// 93.336 us; speedup vs baseline: 1.2674x; 1.2674x over previous
//
#include <hip/hip_runtime.h>
#include <stdint.h>

typedef _Float16 half_t;
typedef __attribute__((ext_vector_type(8))) _Float16 f16x8;
typedef __attribute__((ext_vector_type(4))) _Float16 f16x4;
typedef __attribute__((ext_vector_type(2))) __fp16 fp16x2;
typedef __attribute__((ext_vector_type(4))) float f32x4;
typedef __attribute__((ext_vector_type(16))) float f32x16;
typedef __attribute__((ext_vector_type(4))) uint32_t u32x4;
typedef __attribute__((ext_vector_type(2))) int i32x2;

#define DEVI __device__ __forceinline__

static constexpr int Bn = 4, Cc = 256, Nn = 4096, PD = 32;
static constexpr float L2E = 1.44269504089f;

// persistent f16 intermediates (module-scope device memory; fully rewritten every call)
__device__ half_t g_Q[(size_t)Bn * Nn * PD];   // [b][n][d]
__device__ half_t g_K[(size_t)Bn * Nn * PD];   // [b][n][d]  (= k^T)
__device__ half_t g_V[(size_t)Bn * Cc * Nn];   // [b][e][n]

DEVI f16x8 cvt8(float4 a, float4 b) {
    f16x8 r;
    r[0] = (_Float16)a.x; r[1] = (_Float16)a.y; r[2] = (_Float16)a.z; r[3] = (_Float16)a.w;
    r[4] = (_Float16)b.x; r[5] = (_Float16)b.y; r[6] = (_Float16)b.z; r[7] = (_Float16)b.w;
    return r;
}

DEVI uint32_t pkrtz(float a, float b) {
    fp16x2 h = __builtin_amdgcn_cvt_pkrtz(a, b);
    return __builtin_bit_cast(uint32_t, h);
}

DEVI float asf(int u) { return __builtin_bit_cast(float, u); }
DEVI int   asi(float f) { return __builtin_bit_cast(int, f); }

// lane i<32 gets {own, partner}; lane i>=32 gets {partner, own} — use symmetric ops.
DEVI i32x2 pl32swap(int a, int b) {
    return __builtin_amdgcn_permlane32_swap(a, b, false, false);
}

// async global->LDS, 16B per lane; LDS dest is wave-uniform base + lane*16
DEVI void gll16(const void* g, void* l) {
    auto gp = (const __attribute__((address_space(1))) uint32_t*)(uintptr_t)g;
    auto lp = (__attribute__((address_space(3))) uint32_t*)(uintptr_t)l;
    __builtin_amdgcn_global_load_lds(gp, lp, 16, 0, 0);
}

// ---------------- projection: Q,K,V = W @ x (+bias), f16 outputs ----------------
__global__ __launch_bounds__(256, 1) void proj_kernel(
    const float* __restrict__ x,
    const float* __restrict__ Wq, const float* __restrict__ bq,
    const float* __restrict__ Wk, const float* __restrict__ bk,
    const float* __restrict__ Wv, const float* __restrict__ bv)
{
    __shared__ __align__(16) half_t xt[64 * 40];   // [n][c] tile, pad 32->40

    const int b    = blockIdx.x >> 6;
    const int n0   = (blockIdx.x & 63) * 64;
    const int t    = threadIdx.x;
    const int w    = t >> 6;
    const int lane = t & 63;
    const int l15  = lane & 15, g = lane >> 4;

    f32x4 qk_acc[4] = {};
    f32x4 v_acc[4][4] = {};

    const float* wrow_qk = (w < 2) ? (Wq + (size_t)(16 * w + l15) * Cc)
                                   : (Wk + (size_t)(16 * (w - 2) + l15) * Cc);

    for (int cs = 0; cs < 8; ++cs) {
        const int c0 = cs * 32;
        {
            const int nl = t & 63;
            const int cg = t >> 6;
            const float* xp = x + ((size_t)(b * Cc + c0 + cg * 8)) * Nn + n0 + nl;
            float f[8];
#pragma unroll
            for (int q = 0; q < 8; ++q) f[q] = xp[(size_t)q * Nn];
            f16x4 h0, h1;
#pragma unroll
            for (int q = 0; q < 4; ++q) { h0[q] = (_Float16)f[q]; h1[q] = (_Float16)f[q + 4]; }
            *(f16x4*)&xt[nl * 40 + cg * 8]     = h0;
            *(f16x4*)&xt[nl * 40 + cg * 8 + 4] = h1;
        }
        __syncthreads();

        f16x8 xf[4];
#pragma unroll
        for (int nf = 0; nf < 4; ++nf)
            xf[nf] = *(const f16x8*)&xt[(nf * 16 + l15) * 40 + g * 8];

        {
            const float* wp = wrow_qk + c0 + g * 8;
            const f16x8 af = cvt8(*(const float4*)wp, *(const float4*)(wp + 4));
#pragma unroll
            for (int nt = 0; nt < 4; ++nt)
                qk_acc[nt] = __builtin_amdgcn_mfma_f32_16x16x32_f16(af, xf[nt], qk_acc[nt], 0, 0, 0);
        }
#pragma unroll
        for (int et = 0; et < 4; ++et) {
            const int e = (w * 4 + et) * 16 + l15;
            const float* wp = Wv + (size_t)e * Cc + c0 + g * 8;
            const f16x8 wf = cvt8(*(const float4*)wp, *(const float4*)(wp + 4));
#pragma unroll
            for (int nf = 0; nf < 4; ++nf)
                v_acc[et][nf] = __builtin_amdgcn_mfma_f32_16x16x32_f16(xf[nf], wf, v_acc[et][nf], 0, 0, 0);
        }
        __syncthreads();
    }

    {
        const float* bias = (w < 2) ? bq : bk;
        const int dbase = 16 * (w & 1) + 4 * g;
        float bb[4];
#pragma unroll
        for (int r = 0; r < 4; ++r) bb[r] = bias[dbase + r];
        half_t* dst = (w < 2) ? g_Q : g_K;
#pragma unroll
        for (int nt = 0; nt < 4; ++nt) {
            const int n = n0 + nt * 16 + l15;
            f16x4 h;
#pragma unroll
            for (int r = 0; r < 4; ++r) h[r] = (_Float16)(qk_acc[nt][r] + bb[r]);
            *(f16x4*)&dst[((size_t)b * Nn + n) * PD + dbase] = h;
        }
    }
#pragma unroll
    for (int et = 0; et < 4; ++et) {
        const int e = (w * 4 + et) * 16 + l15;
        const float bve = bv[e];
#pragma unroll
        for (int nf = 0; nf < 4; ++nf) {
            const int n = n0 + nf * 16 + 4 * g;
            f16x4 h;
#pragma unroll
            for (int r = 0; r < 4; ++r) h[r] = (_Float16)(v_acc[et][nf][r] + bve);
            *(f16x4*)&g_V[((size_t)b * Cc + e) * Nn + n] = h;
        }
    }
}

// ------------- fused flash attention + residual (v10 = v9 + builtin permlane swaps) --
// v8/v9 bug: inline-asm "v_permlane32_swap %0,%1" with a==bsw (same SSA value)
// lets regalloc COALESCE both operands into one register -> in-place half-swap,
// reduce returns partner's value instead of max/sum.  The builtin returns both
// halves as v2i32 (SSA) — aliasing impossible.
__global__ __launch_bounds__(256, 2) void attn_kernel(
    const float* __restrict__ x, const float* __restrict__ gamma_p, float* __restrict__ out)
{
    __shared__ __align__(16) half_t V_lds[2][128 * 64];   // linear [e][n], 32KB
    __shared__ float mrg[2][64][36];                      // epilogue merge, 18.4KB
    __shared__ float mx[2][2][32];                        // [kk][mh][m-local]
    __shared__ float lx[2][2][32];

    const int blk = blockIdx.x;
    const int grp = blk & 7;                // (b, eh): XCD round-robin group
    const int mt  = blk >> 3;
    const int b   = grp >> 1;
    const int eh  = grp & 1;
    const int e0  = eh * 128;

    const int t    = threadIdx.x;
    const int w    = t >> 6;
    const int lane = t & 63;
    const int l31  = lane & 31;
    const int hi   = lane >> 5;
    const int mh   = w >> 1, kk = w & 1;
    const int mrow0 = mt * 64 + mh * 32;    // wave's 32 m-rows

    const half_t* Kb  = g_K + (size_t)b * Nn * PD;
    const half_t* Vbg = g_V + (size_t)b * Cc * Nn;

    // Q frags: rows m = mrow0 + l31; d-slices hi*8 (dstep0) and 16+hi*8 (dstep1)
    const half_t* qp = g_Q + ((size_t)b * Nn + mrow0 + l31) * PD + hi * 8;
    const f16x8 q0 = *(const f16x8*)qp;
    const f16x8 q1 = *(const f16x8*)(qp + 16);

    // V gll: lane covers (row = lane>>3, chunk lane&7); source col pre-swizzled
    const int vrow = lane >> 3;
    const int vcol = (((lane & 7) ^ vrow) * 8);
    const half_t* vptr[4];
#pragma unroll
    for (int ch = 0; ch < 4; ++ch)
        vptr[ch] = Vbg + (size_t)(e0 + w * 32 + ch * 8 + vrow) * Nn + vcol;

    // V read offsets (f16 units): row el=et*32+l31; global chunks kk*4+hi (ks0),
    // kk*4+2+hi (ks1), XOR'd with the row swizzle e7.
    const int e7   = l31 & 7;
    const int off0 = (((kk * 4) + hi) ^ e7) * 8;
    const int off1 = (((kk * 4) + 2 + hi) ^ e7) * 8;

    f32x16 acc[4] = {};   // [et]: col e = e0+et*32+l31, row m = mrow0+(r&3)+8*(r>>2)+4*hi
    float run_m = -1e30f, run_l = 0.f;
    const f32x16 zero16 = {};

    f32x16 s;             // current tile's S^T (rows n in regs, col m = l31)
    f16x8 kq0, kq1;       // K frags for NEXT tile

    // ---- prologue: QK(0) direct; gll V(0); prefetch K(1) ----
    {
        const half_t* kp0 = Kb + (size_t)(kk * 32 + l31) * PD + hi * 8;
        const f16x8 ka = *(const f16x8*)kp0;
        const f16x8 kb = *(const f16x8*)(kp0 + 16);
        s = __builtin_amdgcn_mfma_f32_32x32x16_f16(ka, q0, zero16, 0, 0, 0);
        s = __builtin_amdgcn_mfma_f32_32x32x16_f16(kb, q1, s, 0, 0, 0);
    }
#pragma unroll
    for (int ch = 0; ch < 4; ++ch)
        gll16(vptr[ch], &V_lds[0][(w * 32 + ch * 8) * 64]);
    __builtin_amdgcn_sched_barrier(0);
    const half_t* kp = Kb + (size_t)(64 + kk * 32 + l31) * PD + hi * 8;
    kq0 = *(const f16x8*)kp;
    kq1 = *(const f16x8*)(kp + 16);
    __builtin_amdgcn_sched_barrier(0);

    constexpr int NT = Nn / 64;
    for (int i = 0; i < NT; ++i) {
        const int buf = i & 1;
        const bool more = (i + 1 < NT);

        // counted drain: the 4 gll for tile i are the oldest; 2 K loads may stay.
        asm volatile("s_waitcnt vmcnt(2)" ::: "memory");
        __builtin_amdgcn_s_barrier();
        __builtin_amdgcn_sched_barrier(0);

        // ---- softmax in-register (row m = l31; 32 n-values in 16 regs x hi-pair) ----
        float tm = s[0];
#pragma unroll
        for (int r = 1; r < 16; ++r) tm = fmaxf(tm, s[r]);
        {
            const i32x2 rr = pl32swap(asi(tm), asi(tm));
            tm = fmaxf(asf(rr[0]), asf(rr[1]));
        }
        float alpha = 1.f;
        if (__any(tm > run_m + 8.f)) {
            const float nm = fmaxf(run_m, tm);
            alpha = __builtin_amdgcn_exp2f((run_m - nm) * L2E);
            run_m = nm;
            float a16[16];
#pragma unroll
            for (int r = 0; r < 16; ++r)
                a16[r] = __shfl(alpha, (r & 3) + 8 * (r >> 2) + 4 * hi);
#pragma unroll
            for (int et = 0; et < 4; ++et)
#pragma unroll
                for (int r = 0; r < 16; ++r) acc[et][r] *= a16[r];
        }

        const float nms = run_m * L2E;
        float p[16];
#pragma unroll
        for (int r = 0; r < 16; ++r)
            p[r] = __builtin_amdgcn_exp2f(s[r] * L2E - nms);
        float rs = (((p[0] + p[1]) + (p[2] + p[3])) + ((p[4] + p[5]) + (p[6] + p[7])))
                 + (((p[8] + p[9]) + (p[10] + p[11])) + ((p[12] + p[13]) + (p[14] + p[15])));
        {
            const i32x2 rr = pl32swap(asi(rs), asi(rs));
            rs = asf(rr[0]) + asf(rr[1]);
        }
        run_l = run_l * alpha + rs;

        // ---- pack P into PV A-frags: cvt_pkrtz + permlane32_swap (in-register) ----
        f16x8 pa0, pa1;
        {
            const i32x2 r0 = pl32swap((int)pkrtz(p[0], p[1]), (int)pkrtz(p[4], p[5]));
            const i32x2 r1 = pl32swap((int)pkrtz(p[2], p[3]), (int)pkrtz(p[6], p[7]));
            u32x4 d0 = {(uint32_t)r0[0], (uint32_t)r1[0], (uint32_t)r0[1], (uint32_t)r1[1]};
            pa0 = __builtin_bit_cast(f16x8, d0);
            const i32x2 r2 = pl32swap((int)pkrtz(p[8], p[9]),   (int)pkrtz(p[12], p[13]));
            const i32x2 r3 = pl32swap((int)pkrtz(p[10], p[11]), (int)pkrtz(p[14], p[15]));
            u32x4 d1 = {(uint32_t)r2[0], (uint32_t)r3[0], (uint32_t)r2[1], (uint32_t)r3[1]};
            pa1 = __builtin_bit_cast(f16x8, d1);
        }

        // issue gll for tile i+1 into the other buffer
        if (more) {
#pragma unroll
            for (int ch = 0; ch < 4; ++ch) {
                vptr[ch] += 64;
                gll16(vptr[ch], &V_lds[buf ^ 1][(w * 32 + ch * 8) * 64]);
            }
        }
        __builtin_amdgcn_sched_barrier(0);

        // ---- PV: 4 e-tiles x 2 k-steps over wave's 32n half ----
        __builtin_amdgcn_s_setprio(1);
#pragma unroll
        for (int et = 0; et < 4; ++et) {
            const int rowb = (et * 32 + l31) * 64;
            const f16x8 vf0 = *(const f16x8*)&V_lds[buf][rowb + off0];
            const f16x8 vf1 = *(const f16x8*)&V_lds[buf][rowb + off1];
            acc[et] = __builtin_amdgcn_mfma_f32_32x32x16_f16(pa0, vf0, acc[et], 0, 0, 0);
            acc[et] = __builtin_amdgcn_mfma_f32_32x32x16_f16(pa1, vf1, acc[et], 0, 0, 0);
        }
        __builtin_amdgcn_s_setprio(0);

        // ---- QK for tile i+1; prefetch K for i+2 (wrap at tail: keeps vmcnt order) ----
        if (more) {
            s = __builtin_amdgcn_mfma_f32_32x32x16_f16(kq0, q0, zero16, 0, 0, 0);
            s = __builtin_amdgcn_mfma_f32_32x32x16_f16(kq1, q1, s, 0, 0, 0);
            kp += 64 * PD;
            if (i + 2 >= NT) kp = Kb + (size_t)(kk * 32 + l31) * PD + hi * 8;  // dummy
            kq0 = *(const f16x8*)kp;
            kq1 = *(const f16x8*)(kp + 16);
            __builtin_amdgcn_sched_barrier(0);
        }
    }

    // ---- epilogue: publish (m,l); merge kk-pair with exact exp2 correction ----
    if (lane < 32) { mx[kk][mh][l31] = run_m; lx[kk][mh][l31] = run_l; }
    __syncthreads();

    const float mo = mx[kk ^ 1][mh][l31];
    const float lo = lx[kk ^ 1][mh][l31];
    const float M  = fmaxf(run_m, mo);
    const float ssf = __builtin_amdgcn_exp2f((run_m - M) * L2E);
    const float sof = __builtin_amdgcn_exp2f((mo - M) * L2E);
    const float inv = 1.0f / (run_l * ssf + lo * sof);
    float sc16[16], li16[16];
#pragma unroll
    for (int r = 0; r < 16; ++r) {
        const int src = (r & 3) + 8 * (r >> 2) + 4 * hi;
        sc16[r] = __shfl(ssf, src);
        li16[r] = __shfl(inv, src);
    }

    const float gm = gamma_p[0];
#pragma unroll
    for (int h = 0; h < 2; ++h) {
        __syncthreads();
        if (kk == 1) {
#pragma unroll
            for (int e2 = 0; e2 < 2; ++e2) {
                const int et  = 2 * h + e2;
                const int ell = e2 * 32 + l31;
#pragma unroll
                for (int q = 0; q < 4; ++q) {
                    float4 v;
                    v.x = acc[et][4 * q + 0] * sc16[4 * q + 0];
                    v.y = acc[et][4 * q + 1] * sc16[4 * q + 1];
                    v.z = acc[et][4 * q + 2] * sc16[4 * q + 2];
                    v.w = acc[et][4 * q + 3] * sc16[4 * q + 3];
                    *(float4*)&mrg[mh][ell][8 * q + 4 * hi] = v;
                }
            }
        }
        __syncthreads();
        if (kk == 0) {
#pragma unroll
            for (int e2 = 0; e2 < 2; ++e2) {
                const int et  = 2 * h + e2;
                const int ell = e2 * 32 + l31;
                const int e   = e0 + et * 32 + l31;
#pragma unroll
                for (int q = 0; q < 4; ++q) {
                    const float4 part = *(const float4*)&mrg[mh][ell][8 * q + 4 * hi];
                    const size_t idx = ((size_t)b * Cc + e) * Nn + mrow0 + 8 * q + 4 * hi;
                    const float4 xin = *(const float4*)&x[idx];
                    float4 o;
                    o.x = gm * (acc[et][4 * q + 0] * sc16[4 * q + 0] + part.x) * li16[4 * q + 0] + xin.x;
                    o.y = gm * (acc[et][4 * q + 1] * sc16[4 * q + 1] + part.y) * li16[4 * q + 1] + xin.y;
                    o.z = gm * (acc[et][4 * q + 2] * sc16[4 * q + 2] + part.z) * li16[4 * q + 2] + xin.z;
                    o.w = gm * (acc[et][4 * q + 3] * sc16[4 * q + 3] + part.w) * li16[4 * q + 3] + xin.w;
                    *(float4*)&out[idx] = o;
                }
            }
        }
    }
}

extern "C" void kernel_launch(void* const* d_in, const int* in_sizes, int n_in,
                              void* d_out, int out_size, void* d_ws, size_t ws_size,
                              hipStream_t stream) {
    (void)in_sizes; (void)n_in; (void)out_size; (void)d_ws; (void)ws_size;
    const float* x  = (const float*)d_in[0];
    const float* Wq = (const float*)d_in[1];
    const float* bq = (const float*)d_in[2];
    const float* Wk = (const float*)d_in[3];
    const float* bk = (const float*)d_in[4];
    const float* Wv = (const float*)d_in[5];
    const float* bv = (const float*)d_in[6];
    const float* gm = (const float*)d_in[7];
    float* out = (float*)d_out;

    proj_kernel<<<256, 256, 0, stream>>>(x, Wq, bq, Wk, bk, Wv, bv);
    attn_kernel<<<512, 256, 0, stream>>>(x, gm, out);
}

// Round 12
// 81.341 us; speedup vs baseline: 1.4544x; 1.1475x over previous
//
#include <hip/hip_runtime.h>
#include <stdint.h>

typedef _Float16 half_t;
typedef __attribute__((ext_vector_type(8))) _Float16 f16x8;
typedef __attribute__((ext_vector_type(4))) _Float16 f16x4;
typedef __attribute__((ext_vector_type(2))) __fp16 fp16x2;
typedef __attribute__((ext_vector_type(4))) float f32x4;
typedef __attribute__((ext_vector_type(16))) float f32x16;
typedef __attribute__((ext_vector_type(4))) uint32_t u32x4;
typedef __attribute__((ext_vector_type(2))) int i32x2;

#define DEVI __device__ __forceinline__

static constexpr int Bn = 4, Cc = 256, Nn = 4096, PD = 32;
static constexpr float L2E = 1.44269504089f;

// persistent f16 intermediates (module-scope device memory; fully rewritten every call)
__device__ half_t g_Q[(size_t)Bn * Nn * PD];   // [b][n][d]
__device__ half_t g_K[(size_t)Bn * Nn * PD];   // [b][n][d]  (= k^T)
__device__ half_t g_V[(size_t)Bn * Cc * Nn];   // [b][e][n]

DEVI f16x8 cvt8(float4 a, float4 b) {
    f16x8 r;
    r[0] = (_Float16)a.x; r[1] = (_Float16)a.y; r[2] = (_Float16)a.z; r[3] = (_Float16)a.w;
    r[4] = (_Float16)b.x; r[5] = (_Float16)b.y; r[6] = (_Float16)b.z; r[7] = (_Float16)b.w;
    return r;
}

DEVI uint32_t pkrtz(float a, float b) {
    fp16x2 h = __builtin_amdgcn_cvt_pkrtz(a, b);
    return __builtin_bit_cast(uint32_t, h);
}

DEVI float asf(int u) { return __builtin_bit_cast(float, u); }
DEVI int   asi(float f) { return __builtin_bit_cast(int, f); }

DEVI i32x2 pl32swap(int a, int b) {
    return __builtin_amdgcn_permlane32_swap(a, b, false, false);
}

// async global->LDS, 16B per lane; LDS dest is wave-uniform base + lane*16
DEVI void gll16(const void* g, void* l) {
    auto gp = (const __attribute__((address_space(1))) uint32_t*)(uintptr_t)g;
    auto lp = (__attribute__((address_space(3))) uint32_t*)(uintptr_t)l;
    __builtin_amdgcn_global_load_lds(gp, lp, 16, 0, 0);
}

// ---------------- projection: Q,K,V = W @ x (+bias), f16 outputs ----------------
__global__ __launch_bounds__(256, 1) void proj_kernel(
    const float* __restrict__ x,
    const float* __restrict__ Wq, const float* __restrict__ bq,
    const float* __restrict__ Wk, const float* __restrict__ bk,
    const float* __restrict__ Wv, const float* __restrict__ bv)
{
    __shared__ __align__(16) half_t xt[64 * 40];   // [n][c] tile, pad 32->40

    const int b    = blockIdx.x >> 6;
    const int n0   = (blockIdx.x & 63) * 64;
    const int t    = threadIdx.x;
    const int w    = t >> 6;
    const int lane = t & 63;
    const int l15  = lane & 15, g = lane >> 4;

    f32x4 qk_acc[4] = {};
    f32x4 v_acc[4][4] = {};

    const float* wrow_qk = (w < 2) ? (Wq + (size_t)(16 * w + l15) * Cc)
                                   : (Wk + (size_t)(16 * (w - 2) + l15) * Cc);

    for (int cs = 0; cs < 8; ++cs) {
        const int c0 = cs * 32;
        {
            const int nl = t & 63;
            const int cg = t >> 6;
            const float* xp = x + ((size_t)(b * Cc + c0 + cg * 8)) * Nn + n0 + nl;
            float f[8];
#pragma unroll
            for (int q = 0; q < 8; ++q) f[q] = xp[(size_t)q * Nn];
            f16x4 h0, h1;
#pragma unroll
            for (int q = 0; q < 4; ++q) { h0[q] = (_Float16)f[q]; h1[q] = (_Float16)f[q + 4]; }
            *(f16x4*)&xt[nl * 40 + cg * 8]     = h0;
            *(f16x4*)&xt[nl * 40 + cg * 8 + 4] = h1;
        }
        __syncthreads();

        f16x8 xf[4];
#pragma unroll
        for (int nf = 0; nf < 4; ++nf)
            xf[nf] = *(const f16x8*)&xt[(nf * 16 + l15) * 40 + g * 8];

        {
            const float* wp = wrow_qk + c0 + g * 8;
            const f16x8 af = cvt8(*(const float4*)wp, *(const float4*)(wp + 4));
#pragma unroll
            for (int nt = 0; nt < 4; ++nt)
                qk_acc[nt] = __builtin_amdgcn_mfma_f32_16x16x32_f16(af, xf[nt], qk_acc[nt], 0, 0, 0);
        }
#pragma unroll
        for (int et = 0; et < 4; ++et) {
            const int e = (w * 4 + et) * 16 + l15;
            const float* wp = Wv + (size_t)e * Cc + c0 + g * 8;
            const f16x8 wf = cvt8(*(const float4*)wp, *(const float4*)(wp + 4));
#pragma unroll
            for (int nf = 0; nf < 4; ++nf)
                v_acc[et][nf] = __builtin_amdgcn_mfma_f32_16x16x32_f16(xf[nf], wf, v_acc[et][nf], 0, 0, 0);
        }
        __syncthreads();
    }

    {
        const float* bias = (w < 2) ? bq : bk;
        const int dbase = 16 * (w & 1) + 4 * g;
        float bb[4];
#pragma unroll
        for (int r = 0; r < 4; ++r) bb[r] = bias[dbase + r];
        half_t* dst = (w < 2) ? g_Q : g_K;
#pragma unroll
        for (int nt = 0; nt < 4; ++nt) {
            const int n = n0 + nt * 16 + l15;
            f16x4 h;
#pragma unroll
            for (int r = 0; r < 4; ++r) h[r] = (_Float16)(qk_acc[nt][r] + bb[r]);
            *(f16x4*)&dst[((size_t)b * Nn + n) * PD + dbase] = h;
        }
    }
#pragma unroll
    for (int et = 0; et < 4; ++et) {
        const int e = (w * 4 + et) * 16 + l15;
        const float bve = bv[e];
#pragma unroll
        for (int nf = 0; nf < 4; ++nf) {
            const int n = n0 + nf * 16 + 4 * g;
            f16x4 h;
#pragma unroll
            for (int r = 0; r < 4; ++r) h[r] = (_Float16)(v_acc[et][nf][r] + bve);
            *(f16x4*)&g_V[((size_t)b * Cc + e) * Nn + n] = h;
        }
    }
}

// ------- fused flash attention + residual (v11: R=1, 8-wave block, KVBLK=128) -------
// Grid 256 = 1 block/CU; block = 512 thr = 8 waves (mh = w>>2 over 64m, kk = w&3
// over 128n tile).  Block covers ALL 256 e -> QK/softmax computed ONCE (R=1).
// Wave: S[32n(kk)][32m(mh)] via 2 mfma_32x32x16; in-register softmax + P pack
// (v10-verified); PV: 8 et x 2 ks = 16 MFMA (full 256e, wave-local n-half).
// V [256e][128n] dbuf in 128KB LDS via gll (pre-swizzled source, 16-chunk rows);
// counted vmcnt(2) + raw barrier per iter (NT=32).  Epilogue: 4-way kk merge
// (exact exp2 correction) staged through V_lds in 2 et-rounds.
__global__ __launch_bounds__(512, 2) void attn_kernel(
    const float* __restrict__ x, const float* __restrict__ gamma_p, float* __restrict__ out)
{
    __shared__ __align__(16) half_t V_lds[2][256 * 128];  // 128KB
    __shared__ float mx[2][4][32];                        // [mh][kk][m-local]
    __shared__ float lx[2][4][32];

    const int blk = blockIdx.x;
    const int grp = blk & 7;                 // XCD id; b = grp>>1 (V slice L2-local)
    const int b   = grp >> 1;
    const int mt  = ((blk >> 3) << 1) | (grp & 1);   // 0..63

    const int t    = threadIdx.x;
    const int w    = t >> 6;                 // 0..7
    const int lane = t & 63;
    const int l31  = lane & 31;
    const int hi   = lane >> 5;
    const int kk   = w & 3;                  // n-quarter of 128-tile
    const int mh   = w >> 2;                 // m-half of 64m
    const int mrow0 = mt * 64 + mh * 32;

    const half_t* Kb  = g_K + (size_t)b * Nn * PD;
    const half_t* Vbg = g_V + (size_t)b * Cc * Nn;

    // Q frags: rows m = mrow0 + l31; d-slices hi*8 / 16+hi*8
    const half_t* qp = g_Q + ((size_t)b * Nn + mrow0 + l31) * PD + hi * 8;
    const f16x8 q0 = *(const f16x8*)qp;
    const f16x8 q1 = *(const f16x8*)(qp + 16);

    // V gll source (per-lane): e-row vr = w*4 + (lane>>4) (+32 per round),
    // chunk pc = lane&15, source col pre-swizzled: n-chunk = pc ^ (vr&7)
    const int vr = w * 4 + (lane >> 4);
    const half_t* vb = Vbg + (size_t)vr * Nn + (((lane & 15) ^ (vr & 7)) * 8);

    // PV V-read offsets: row el = et*32+l31 (stride 128 f16 = 256B, 16 chunks);
    // logical chunk c = kk*4 + ks*2 + hi, physical = c ^ (row&7)
    const int e7   = l31 & 7;
    const int off0 = (((kk * 4) + hi) ^ e7) * 8;
    const int off1 = (((kk * 4) + 2 + hi) ^ e7) * 8;

    f32x16 acc[8] = {};   // [et]: col e = et*32+l31, row m = mrow0+(r&3)+8*(r>>2)+4*hi
    float run_m = -1e30f, run_l = 0.f;
    const f32x16 zero16 = {};

    f32x16 s;             // current tile's S^T
    f16x8 kq0, kq1;       // K frags for NEXT tile

    // ---- prologue: QK(0) direct; gll V(0); prefetch K(1) ----
    {
        const half_t* kp0 = Kb + (size_t)(kk * 32 + l31) * PD + hi * 8;
        const f16x8 ka = *(const f16x8*)kp0;
        const f16x8 kb = *(const f16x8*)(kp0 + 16);
        s = __builtin_amdgcn_mfma_f32_32x32x16_f16(ka, q0, zero16, 0, 0, 0);
        s = __builtin_amdgcn_mfma_f32_32x32x16_f16(kb, q1, s, 0, 0, 0);
    }
#pragma unroll
    for (int rr = 0; rr < 8; ++rr)
        gll16(vb + (size_t)rr * 32 * Nn, &V_lds[0][rr * 4096 + w * 512]);
    __builtin_amdgcn_sched_barrier(0);
    const half_t* kp = Kb + (size_t)(128 + kk * 32 + l31) * PD + hi * 8;
    kq0 = *(const f16x8*)kp;
    kq1 = *(const f16x8*)(kp + 16);
    __builtin_amdgcn_sched_barrier(0);

    constexpr int NT = Nn / 128;
    for (int i = 0; i < NT; ++i) {
        const int buf = i & 1;
        const bool more = (i + 1 < NT);

        // counted drain: the 8 gll for tile i are the oldest; 2 K loads may stay.
        asm volatile("s_waitcnt vmcnt(2)" ::: "memory");
        __builtin_amdgcn_s_barrier();
        __builtin_amdgcn_sched_barrier(0);

        // ---- softmax in-register (row m = l31; 32 n in 16 regs x hi-pair) ----
        float tm = s[0];
#pragma unroll
        for (int r = 1; r < 16; ++r) tm = fmaxf(tm, s[r]);
        {
            const i32x2 rr = pl32swap(asi(tm), asi(tm));
            tm = fmaxf(asf(rr[0]), asf(rr[1]));
        }
        float alpha = 1.f;
        if (__any(tm > run_m + 8.f)) {
            const float nm = fmaxf(run_m, tm);
            alpha = __builtin_amdgcn_exp2f((run_m - nm) * L2E);
            run_m = nm;
            float a16[16];
#pragma unroll
            for (int r = 0; r < 16; ++r)
                a16[r] = __shfl(alpha, (r & 3) + 8 * (r >> 2) + 4 * hi);
#pragma unroll
            for (int et = 0; et < 8; ++et)
#pragma unroll
                for (int r = 0; r < 16; ++r) acc[et][r] *= a16[r];
        }

        const float nms = run_m * L2E;
        float p[16];
#pragma unroll
        for (int r = 0; r < 16; ++r)
            p[r] = __builtin_amdgcn_exp2f(s[r] * L2E - nms);
        float rs = (((p[0] + p[1]) + (p[2] + p[3])) + ((p[4] + p[5]) + (p[6] + p[7])))
                 + (((p[8] + p[9]) + (p[10] + p[11])) + ((p[12] + p[13]) + (p[14] + p[15])));
        {
            const i32x2 rr = pl32swap(asi(rs), asi(rs));
            rs = asf(rr[0]) + asf(rr[1]);
        }
        run_l = run_l * alpha + rs;

        // ---- pack P into PV A-frags (v10-verified) ----
        f16x8 pa0, pa1;
        {
            const i32x2 r0 = pl32swap((int)pkrtz(p[0], p[1]), (int)pkrtz(p[4], p[5]));
            const i32x2 r1 = pl32swap((int)pkrtz(p[2], p[3]), (int)pkrtz(p[6], p[7]));
            u32x4 d0 = {(uint32_t)r0[0], (uint32_t)r1[0], (uint32_t)r0[1], (uint32_t)r1[1]};
            pa0 = __builtin_bit_cast(f16x8, d0);
            const i32x2 r2 = pl32swap((int)pkrtz(p[8], p[9]),   (int)pkrtz(p[12], p[13]));
            const i32x2 r3 = pl32swap((int)pkrtz(p[10], p[11]), (int)pkrtz(p[14], p[15]));
            u32x4 d1 = {(uint32_t)r2[0], (uint32_t)r3[0], (uint32_t)r2[1], (uint32_t)r3[1]};
            pa1 = __builtin_bit_cast(f16x8, d1);
        }

        // issue gll for tile i+1 into the other buffer
        if (more) {
#pragma unroll
            for (int rr = 0; rr < 8; ++rr)
                gll16(vb + 128 + (size_t)rr * 32 * Nn, &V_lds[buf ^ 1][rr * 4096 + w * 512]);
            vb += 128;
        }
        __builtin_amdgcn_sched_barrier(0);

        // ---- PV: 8 e-tiles x 2 k-steps over wave's 32n quarter ----
        __builtin_amdgcn_s_setprio(1);
#pragma unroll
        for (int et = 0; et < 8; ++et) {
            const int rowb = (et * 32 + l31) * 128;
            const f16x8 vf0 = *(const f16x8*)&V_lds[buf][rowb + off0];
            const f16x8 vf1 = *(const f16x8*)&V_lds[buf][rowb + off1];
            acc[et] = __builtin_amdgcn_mfma_f32_32x32x16_f16(pa0, vf0, acc[et], 0, 0, 0);
            acc[et] = __builtin_amdgcn_mfma_f32_32x32x16_f16(pa1, vf1, acc[et], 0, 0, 0);
        }
        __builtin_amdgcn_s_setprio(0);

        // ---- QK for tile i+1; prefetch K for i+2 (tail-wrapped) ----
        if (more) {
            s = __builtin_amdgcn_mfma_f32_32x32x16_f16(kq0, q0, zero16, 0, 0, 0);
            s = __builtin_amdgcn_mfma_f32_32x32x16_f16(kq1, q1, s, 0, 0, 0);
            kp += 128 * PD;
            if (i + 2 >= NT) kp = Kb + (size_t)(kk * 32 + l31) * PD + hi * 8;  // dummy
            kq0 = *(const f16x8*)kp;
            kq1 = *(const f16x8*)(kp + 16);
            __builtin_amdgcn_sched_barrier(0);
        }
    }

    // ---- epilogue: 4-way kk merge with exact exp2 correction ----
    if (lane < 32) { mx[mh][kk][l31] = run_m; lx[mh][kk][l31] = run_l; }
    __syncthreads();

    float sc16[16], li16[16];
    {
        const float m0 = mx[mh][0][l31], m1 = mx[mh][1][l31];
        const float m2 = mx[mh][2][l31], m3 = mx[mh][3][l31];
        const float M  = fmaxf(fmaxf(m0, m1), fmaxf(m2, m3));
        const float L  = lx[mh][0][l31] * __builtin_amdgcn_exp2f((m0 - M) * L2E)
                       + lx[mh][1][l31] * __builtin_amdgcn_exp2f((m1 - M) * L2E)
                       + lx[mh][2][l31] * __builtin_amdgcn_exp2f((m2 - M) * L2E)
                       + lx[mh][3][l31] * __builtin_amdgcn_exp2f((m3 - M) * L2E);
        const float ssf = __builtin_amdgcn_exp2f((run_m - M) * L2E);
        const float inv = 1.0f / L;
#pragma unroll
        for (int r = 0; r < 16; ++r) {
            const int src = (r & 3) + 8 * (r >> 2) + 4 * hi;
            sc16[r] = __shfl(ssf, src);
            li16[r] = __shfl(inv, src);
        }
    }
    __syncthreads();   // all mx/lx reads done before mrg overwrites V_lds

    const float gm = gamma_p[0];
    float4* mrg = (float4*)&V_lds[0][0];   // [slot 0..31][q 0..3][lane 0..63]
#pragma unroll
    for (int h = 0; h < 2; ++h) {
        // write: wave w publishes its 4 ets of this round, scaled by own ssf
#pragma unroll
        for (int j = 0; j < 4; ++j) {
            const int et = h * 4 + j;
#pragma unroll
            for (int q = 0; q < 4; ++q) {
                float4 v;
                v.x = acc[et][4 * q + 0] * sc16[4 * q + 0];
                v.y = acc[et][4 * q + 1] * sc16[4 * q + 1];
                v.z = acc[et][4 * q + 2] * sc16[4 * q + 2];
                v.w = acc[et][4 * q + 3] * sc16[4 * q + 3];
                mrg[((w * 4 + j) * 4 + q) * 64 + lane] = v;
            }
        }
        __syncthreads();
        // read: wave (mh,kk) merges the 4 kk-partials for et = h*4+kk, writes out
        {
            const int et = h * 4 + kk;
            const int e  = et * 32 + l31;
#pragma unroll
            for (int q = 0; q < 4; ++q) {
                float4 s0 = mrg[(((mh * 4 + 0) * 4 + kk) * 4 + q) * 64 + lane];
                float4 s1 = mrg[(((mh * 4 + 1) * 4 + kk) * 4 + q) * 64 + lane];
                float4 s2 = mrg[(((mh * 4 + 2) * 4 + kk) * 4 + q) * 64 + lane];
                float4 s3 = mrg[(((mh * 4 + 3) * 4 + kk) * 4 + q) * 64 + lane];
                const size_t idx = ((size_t)b * Cc + e) * Nn + mrow0 + 8 * q + 4 * hi;
                const float4 xin = *(const float4*)&x[idx];
                float4 o;
                o.x = gm * (s0.x + s1.x + s2.x + s3.x) * li16[4 * q + 0] + xin.x;
                o.y = gm * (s0.y + s1.y + s2.y + s3.y) * li16[4 * q + 1] + xin.y;
                o.z = gm * (s0.z + s1.z + s2.z + s3.z) * li16[4 * q + 2] + xin.z;
                o.w = gm * (s0.w + s1.w + s2.w + s3.w) * li16[4 * q + 3] + xin.w;
                *(float4*)&out[idx] = o;
            }
        }
        __syncthreads();   // readers done before next round's writes
    }
}

extern "C" void kernel_launch(void* const* d_in, const int* in_sizes, int n_in,
                              void* d_out, int out_size, void* d_ws, size_t ws_size,
                              hipStream_t stream) {
    (void)in_sizes; (void)n_in; (void)out_size; (void)d_ws; (void)ws_size;
    const float* x  = (const float*)d_in[0];
    const float* Wq = (const float*)d_in[1];
    const float* bq = (const float*)d_in[2];
    const float* Wk = (const float*)d_in[3];
    const float* bk = (const float*)d_in[4];
    const float* Wv = (const float*)d_in[5];
    const float* bv = (const float*)d_in[6];
    const float* gm = (const float*)d_in[7];
    float* out = (float*)d_out;

    proj_kernel<<<256, 256, 0, stream>>>(x, Wq, bq, Wk, bk, Wv, bv);
    attn_kernel<<<256, 512, 0, stream>>>(x, gm, out);
}